// Round 3
// baseline (434.389 us; speedup 1.0000x reference)
//
#include <hip/hip_runtime.h>

// SPA (second-price auction) payment kernel.
// x: (BATCH, 16) fp32. Per row: top-2 (m1, m2). out[j] = (x[j]==m1 ? m2 : m1), clamp >= 0.
// Tie semantics: if >=2 elements equal m1 then m2==m1, so the elementwise form
// matches the reference's first-argmax form exactly (absmax 0 in R1/R2).
//
// R3 structure: ONE THREAD = ONE ROW (16 floats = 4 contiguous float4 loads).
// - zero cross-lane ops (R1/R2's dependent shfl_xor rounds are gone)
// - 4 independent loads in flight per thread
// - per load instr lanes stride 64B; the 4 unrolled loads consume every byte,
//   L1 serves the line re-hits -> HBM traffic identical to fully-coalesced.

typedef float f32x4 __attribute__((ext_vector_type(4)));

__device__ __forceinline__ void top2_quad(f32x4 v, float& m1, float& m2) {
    float a = fmaxf(v.x, v.y), b = fminf(v.x, v.y);
    float c = fmaxf(v.z, v.w), d = fminf(v.z, v.w);
    m1 = fmaxf(a, c);
    m2 = fmaxf(fminf(a, c), fmaxf(b, d));
}

__device__ __forceinline__ void merge2(float& m1, float& m2, float n1, float n2) {
    float hi = fmaxf(m1, n1);
    float lo = fminf(m1, n1);
    m1 = hi;
    m2 = fmaxf(lo, fmaxf(m2, n2));
}

__device__ __forceinline__ f32x4 payment(f32x4 v, float m1, float m2) {
    f32x4 o;
    o.x = fmaxf((v.x == m1) ? m2 : m1, 0.0f);
    o.y = fmaxf((v.y == m1) ? m2 : m1, 0.0f);
    o.z = fmaxf((v.z == m1) ? m2 : m1, 0.0f);
    o.w = fmaxf((v.w == m1) ? m2 : m1, 0.0f);
    return o;
}

__global__ __launch_bounds__(256) void _SpaPayment_88399016886488_kernel(
    const f32x4* __restrict__ x, f32x4* __restrict__ out, int nrows) {
    int t = blockIdx.x * blockDim.x + threadIdx.x;
    if (t >= nrows) return;

    const f32x4* p = x + (size_t)t * 4;
    f32x4 v0 = p[0];
    f32x4 v1 = p[1];
    f32x4 v2 = p[2];
    f32x4 v3 = p[3];

    float a1, a2, b1, b2, c1, c2, d1, d2;
    top2_quad(v0, a1, a2);
    top2_quad(v1, b1, b2);
    top2_quad(v2, c1, c2);
    top2_quad(v3, d1, d2);
    merge2(a1, a2, b1, b2);
    merge2(c1, c2, d1, d2);
    merge2(a1, a2, c1, c2);   // (a1,a2) = row top-2

    f32x4* q = out + (size_t)t * 4;
    q[0] = payment(v0, a1, a2);
    q[1] = payment(v1, a1, a2);
    q[2] = payment(v2, a1, a2);
    q[3] = payment(v3, a1, a2);
}

extern "C" void kernel_launch(void* const* d_in, const int* in_sizes, int n_in,
                              void* d_out, int out_size, void* d_ws, size_t ws_size,
                              hipStream_t stream) {
    const f32x4* x = (const f32x4*)d_in[0];
    f32x4* out = (f32x4*)d_out;
    int n = in_sizes[0];          // 4194304 * 16 elements
    int nrows = n / 16;           // 4194304 rows, one thread each
    int block = 256;
    int grid = (nrows + block - 1) / block;   // 16384 blocks (exact)
    _SpaPayment_88399016886488_kernel<<<grid, block, 0, stream>>>(x, out, nrows);
}